// Round 3
// baseline (126.211 us; speedup 1.0000x reference)
//
#include <hip/hip_runtime.h>

// HungarianMatcher cost matrix, float4-store version.
// C[q,t] = 5*L1 + 2*focal_cost(tgt_id) - 2*GIoU, fp32 out [14400,1600].
//
// Grid: 900 blocks x 256 threads; each block owns QPB=16 queries.
// Phase A (staging, one-time per block):
//   - focal class costs for 16 queries -> s_cc[16*91] (contiguous logits sweep)
//   - 1600 target boxes -> LDS transposed-float4 SoA: s_x0/s_y0/s_x1/s_y1/s_id,
//     where element [c] packs targets 4c..4c+3 (enables ds_read_b128 feed and
//     float4 output stores of 4 consecutive targets)
//   - 16 query boxes -> s_q[q] = {x0,y0,x1,y1,area}
// Phase B: 16 q x 400 columns = 6400 lane-tasks = exactly 25 slots of 256.
//   Per task: read 5 x b128 from LDS, compute 4 costs, ONE float4 store.
//   100% lane utilization, zero branches, 4x fewer store transactions than
//   the 4B-per-lane version.

#define BLOCK 256
#define QPB   16
#define NC    91
#define NT    1600
#define NCOL  (NT / 4)               // 400
#define SLOTS (QPB * NCOL / BLOCK)   // 25 exactly

__global__ __launch_bounds__(BLOCK, 4) void matcher_kernel(
    const float* __restrict__ logits,   // [14400, 91]
    const float* __restrict__ pboxes,   // [14400, 4] cxcywh
    const float* __restrict__ tboxes,   // [1600, 4]  cxcywh
    const int*   __restrict__ tids,     // [1600]
    float*       __restrict__ out)      // [14400, 1600]
{
    __shared__ float4 s_x0[NCOL], s_y0[NCOL], s_x1[NCOL], s_y1[NCOL]; // 25.6 KB
    __shared__ int4   s_id[NCOL];                                     //  6.4 KB
    __shared__ float  s_cc[QPB * NC];                                 //  5.8 KB
    __shared__ float  s_q[QPB][8];  // x0,y0,x1,y1,area,pad           //  0.5 KB

    const int tid = threadIdx.x;
    const int q0  = blockIdx.x * QPB;

    // ---- Phase A1: focal class costs (COST_CLASS=2 folded in)
    for (int i = tid; i < QPB * NC; i += BLOCK) {
        float x   = logits[(size_t)q0 * NC + i];
        float p   = 1.0f / (1.0f + __expf(-x));
        float omp = 1.0f - p;
        float pos = 0.25f * omp * omp * (-__logf(p   + 1e-8f));
        float neg = 0.75f * p   * p   * (-__logf(omp + 1e-8f));
        s_cc[i] = 2.0f * (pos - neg);
    }

    // ---- Phase A2: targets -> xyxy transposed SoA (conflict-free b32 writes)
    for (int t = tid; t < NT; t += BLOCK) {
        float4 b = ((const float4*)tboxes)[t];
        ((float*)s_x0)[t] = fmaf(-0.5f, b.z, b.x);
        ((float*)s_y0)[t] = fmaf(-0.5f, b.w, b.y);
        ((float*)s_x1)[t] = fmaf( 0.5f, b.z, b.x);
        ((float*)s_y1)[t] = fmaf( 0.5f, b.w, b.y);
        ((int*)  s_id)[t] = tids[t];
    }

    // ---- Phase A3: query boxes
    if (tid < QPB) {
        float4 b = ((const float4*)pboxes)[q0 + tid];
        s_q[tid][0] = fmaf(-0.5f, b.z, b.x);
        s_q[tid][1] = fmaf(-0.5f, b.w, b.y);
        s_q[tid][2] = fmaf( 0.5f, b.z, b.x);
        s_q[tid][3] = fmaf( 0.5f, b.w, b.y);
        s_q[tid][4] = b.z * b.w;            // area
    }
    __syncthreads();

    // ---- Phase B: 25 full slots, one float4 store per lane-task
    #pragma unroll 1
    for (int s = 0; s < SLOTS; ++s) {
        const unsigned idx = (unsigned)(s * BLOCK + tid);   // < 6400
        const unsigned q   = idx / 400u;                    // magic-mul
        const unsigned c   = idx - q * 400u;                // column of 4 targets

        const float qx0 = s_q[q][0], qy0 = s_q[q][1];
        const float qx1 = s_q[q][2], qy1 = s_q[q][3];
        const float qarea = s_q[q][4];
        const float* cc = s_cc + q * NC;

        const float4 X0 = s_x0[c], Y0 = s_y0[c], X1 = s_x1[c], Y1 = s_y1[c];
        const int4   ID = s_id[c];

        const float x0a[4] = {X0.x, X0.y, X0.z, X0.w};
        const float y0a[4] = {Y0.x, Y0.y, Y0.z, Y0.w};
        const float x1a[4] = {X1.x, X1.y, X1.z, X1.w};
        const float y1a[4] = {Y1.x, Y1.y, Y1.z, Y1.w};
        const int   ida[4] = {ID.x, ID.y, ID.z, ID.w};
        float r[4];

        #pragma unroll
        for (int j = 0; j < 4; ++j) {
            const float x0 = x0a[j], y0 = y0a[j], x1 = x1a[j], y1 = y1a[j];

            // L1 in xyxy space: 5*l1 = 2.5*(|dx0+dx1|+|dy0+dy1|) + 5*(|dx1-dx0|+|dy1-dy0|)
            const float dx0 = x0 - qx0, dx1 = x1 - qx1;
            const float dy0 = y0 - qy0, dy1 = y1 - qy1;
            const float e = fabsf(dx0 + dx1) + fabsf(dy0 + dy1);
            const float f = fabsf(dx1 - dx0) + fabsf(dy1 - dy0);

            // intersection / union
            const float iw = fminf(qx1, x1) - fmaxf(qx0, x0);
            const float ih = fminf(qy1, y1) - fmaxf(qy0, y0);
            const float inter = fmaxf(iw, 0.0f) * fmaxf(ih, 0.0f);
            const float tarea = (x1 - x0) * (y1 - y0);
            const float uni   = qarea + tarea - inter;
            const float iou   = inter * __builtin_amdgcn_rcpf(uni);

            // enclosing box
            const float ew = fmaxf(qx1, x1) - fminf(qx0, x0);
            const float eh = fmaxf(qy1, y1) - fminf(qy0, y0);
            const float earea = ew * eh;
            const float g = iou - (earea - uni) * __builtin_amdgcn_rcpf(earea);

            // C = 2*cc + 2.5*e + 5*f - 2*g   (cc already carries the 2x)
            r[j] = fmaf(2.5f, e, fmaf(5.0f, f, fmaf(-2.0f, g, cc[ida[j]])));
        }

        ((float4*)(out + (size_t)(q0 + q) * NT + c * 4u))[0] =
            make_float4(r[0], r[1], r[2], r[3]);
    }
}

extern "C" void kernel_launch(void* const* d_in, const int* in_sizes, int n_in,
                              void* d_out, int out_size, void* d_ws, size_t ws_size,
                              hipStream_t stream) {
    const float* logits = (const float*)d_in[0];   // (16,900,91) fp32
    const float* pboxes = (const float*)d_in[1];   // (16,900,4)  fp32
    const float* tboxes = (const float*)d_in[2];   // (1600,4)    fp32
    const int*   tids   = (const int*)d_in[3];     // (1600,)     int32

    const int nqall = in_sizes[1] / 4;             // 14400
    float* out = (float*)d_out;

    matcher_kernel<<<nqall / QPB, BLOCK, 0, stream>>>(logits, pboxes, tboxes,
                                                      tids, out);
}

// Round 4
// 123.558 us; speedup vs baseline: 1.0215x; 1.0215x over previous
//
#include <hip/hip_runtime.h>

// HungarianMatcher cost matrix — round 2 structure + NON-TEMPORAL stores.
// C[q,t] = 5*L1 + 2*focal_class_cost(tgt_id) - 2*GIoU, fp32 out [14400,1600].
//
// One variable changed vs round 2 (121.4 us, fastest so far): output stores
// use __builtin_nontemporal_store (global_store_dword nt) so the 92.16 MB
// write stream bypasses L2 allocation instead of thrashing the poison-dirty
// L2. Everything else identical: 1800 blocks x 256 threads, QPB=8 queries
// per block, each thread stages its 7 targets in registers, class-cost row
// per query in LDS.

#define BLOCK 256
#define QPB 8
#define NC 91
#define NT 1600
#define TSLOTS ((NT + BLOCK - 1) / BLOCK)   // 7

__global__ __launch_bounds__(BLOCK, 4) void matcher_kernel(
    const float* __restrict__ logits,   // [14400, 91]
    const float* __restrict__ pboxes,   // [14400, 4] cxcywh
    const float* __restrict__ tboxes,   // [1600, 4]  cxcywh
    const int*   __restrict__ tids,     // [1600]
    float*       __restrict__ out)      // [14400, 1600]
{
    __shared__ float s_cc[QPB * NC];
    const int tid = threadIdx.x;
    const int q0  = blockIdx.x * QPB;

    // --- Phase A1: focal class costs for this block's 8 queries (COST_CLASS=2 folded).
    for (int i = tid; i < QPB * NC; i += BLOCK) {
        float x   = logits[(size_t)q0 * NC + i];
        float p   = 1.0f / (1.0f + __expf(-x));
        float omp = 1.0f - p;
        float pos = 0.25f * omp * omp * (-__logf(p   + 1e-8f));
        float neg = 0.75f * p   * p   * (-__logf(omp + 1e-8f));
        s_cc[i] = 2.0f * (pos - neg);
    }

    // --- Phase A2: stage this thread's 7 targets into registers.
    float4 tb[TSLOTS], xy[TSLOTS];
    int    ida[TSLOTS];
    #pragma unroll
    for (int k = 0; k < TSLOTS; ++k) {
        int t = tid + k * BLOCK;
        if (t < NT) {
            float4 b = ((const float4*)tboxes)[t];
            tb[k] = b;
            xy[k] = make_float4(fmaf(-0.5f, b.z, b.x), fmaf(-0.5f, b.w, b.y),
                                fmaf( 0.5f, b.z, b.x), fmaf( 0.5f, b.w, b.y));
            ida[k] = tids[t];
        }
    }
    __syncthreads();

    // --- Phase B: 8 queries x 7 register-resident targets; nt stores.
    #pragma unroll 1
    for (int q = 0; q < QPB; ++q) {
        const int    qg = q0 + q;
        const float4 qb = ((const float4*)pboxes)[qg];     // L1 broadcast
        const float qx0 = fmaf(-0.5f, qb.z, qb.x), qy0 = fmaf(-0.5f, qb.w, qb.y);
        const float qx1 = fmaf( 0.5f, qb.z, qb.x), qy1 = fmaf( 0.5f, qb.w, qb.y);
        const float qarea = qb.z * qb.w;
        const float* cc   = s_cc + q * NC;
        float* outq = out + (size_t)qg * NT;

        #pragma unroll
        for (int k = 0; k < TSLOTS; ++k) {
            int t = tid + k * BLOCK;
            if (t < NT) {                                  // wave-uniform (k=6: wave 0 only)
                float4 b = tb[k], p = xy[k];

                float l1 = fabsf(qb.x - b.x) + fabsf(qb.y - b.y)
                         + fabsf(qb.z - b.z) + fabsf(qb.w - b.w);

                float tarea = b.z * b.w;
                float iw = fminf(qx1, p.z) - fmaxf(qx0, p.x);
                float ih = fminf(qy1, p.w) - fmaxf(qy0, p.y);
                float inter = fmaxf(iw, 0.0f) * fmaxf(ih, 0.0f);
                float uni   = qarea + tarea - inter;
                float iou   = inter * __builtin_amdgcn_rcpf(uni);
                float ew = fmaxf(qx1, p.z) - fminf(qx0, p.x);
                float eh = fmaxf(qy1, p.w) - fminf(qy0, p.y);
                float earea = ew * eh;
                float giou  = iou - (earea - uni) * __builtin_amdgcn_rcpf(earea);

                float c = fmaf(5.0f, l1, cc[ida[k]]) - 2.0f * giou;
                __builtin_nontemporal_store(c, &outq[t]);  // bypass L2 allocation
            }
        }
    }
}

extern "C" void kernel_launch(void* const* d_in, const int* in_sizes, int n_in,
                              void* d_out, int out_size, void* d_ws, size_t ws_size,
                              hipStream_t stream) {
    const float* logits = (const float*)d_in[0];   // (16,900,91) fp32
    const float* pboxes = (const float*)d_in[1];   // (16,900,4)  fp32
    const float* tboxes = (const float*)d_in[2];   // (1600,4)    fp32
    const int*   tids   = (const int*)d_in[3];     // (1600,)     int32

    const int nqall = in_sizes[1] / 4;             // 14400
    float* out = (float*)d_out;

    matcher_kernel<<<nqall / QPB, BLOCK, 0, stream>>>(logits, pboxes, tboxes,
                                                      tids, out);
}